// Round 11
// baseline (100.257 us; speedup 1.0000x reference)
//
#include <hip/hip_runtime.h>
#include <hip/hip_bf16.h>
#include <math.h>

#define T_LEN   7680
#define NSEG    59
#define NBINS   45
#define CH_PB   4      // channels per block
#define NBLK    1024   // 4096 / CH_PB

using bf16x8 = __attribute__((ext_vector_type(8))) short;
using f32x4  = __attribute__((ext_vector_type(4))) float;

__device__ __forceinline__ unsigned f2bf(float f) {
    unsigned u = __builtin_bit_cast(unsigned, f);
    return (u + 0x7FFFu + ((u >> 16) & 1u)) >> 16;   // RNE fp32->bf16
}

// Pure-address-function LDS swizzle (R9/R10-proven).
__device__ __forceinline__ unsigned phys(unsigned a) {
    return a ^ (((a >> 8) & 7u) << 4);
}

// Basis table mt[96][256] bf16 (detrend+window folded; R2-proven math).
__global__ void build_basis_kernel(unsigned short* __restrict__ mt) {
    int j = blockIdx.x, n = threadIdx.x;
    const float TH = 0.02454369260617026f;           // 2*pi/256
    float w = 0.5f - 0.5f * cosf((float)n * TH);     // periodic hann
    float v = 0.f;
    if (j < 90) {
        int k = (j >> 1) + 1;
        int m = (k * n) & 255;                       // exact periodic reduction
        float th = (float)m * TH;
        v = (j & 1) ? (-w * sinf(th)) : (w * cosf(th));
        if (j == 0) v += 0.25f;                      // fold detrend into k=1 re
    }
    mt[j * 256 + n] = (unsigned short)f2bf(v);
}

// R10 structure + ONE change: amdgpu_waves_per_eu(3,3) pins the compiler's
// register budget at 512/3=170, stopping its occupancy-chasing heuristic
// (R10: it targeted ~6 waves/EU -> VGPR=84 -> spilled the laundered breg ->
// 90MB scratch round-trip on the MFMA path -> 99us. R9: same heuristic chose
// remat at VGPR=68 -> L2 reloads inside G -> 63us).
// Ledger: breg HOISTED + laundered (R8/R9). Guards NEVER inside the k0 MFMA
// loop (R3-R5: absmax 4.2e-3). No register prefetch across G (R7). lb is a
// floor not a cap (R6); now the budget is pinned explicitly.
__global__ __launch_bounds__(256, 3) __attribute__((amdgpu_waves_per_eu(3, 3)))
void welch_main_kernel(const float* __restrict__ x,
                       const unsigned short* __restrict__ mt,
                       float* __restrict__ out) {
    __shared__ __align__(16) float          xf[T_LEN];   // 30720 B DMA target
    __shared__ __align__(16) unsigned short xs[8320];    // 16640 B bf16
    __shared__ float psum[2][96];

    const int tid  = threadIdx.x;
    const int lane = tid & 63;
    const int w    = tid >> 6;
    const int ch0  = blockIdx.x * CH_PB;
    const float* gx = x + (size_t)ch0 * T_LEN;

    // DMA one channel into xf: 1920 16B chunks, wave-uniform LDS base,
    // per-lane global source. Zero VGPR cost -> no spill pressure.
    auto issue_x = [&](const float* gxc) {
        #pragma unroll
        for (int i = 0; i < 8; ++i) {
            int base = i * 256 + (tid & ~63);        // wave-uniform chunk base
            if (base < 1920) {                        // wave-uniform guard
                char* lp = (char*)xf + (size_t)base * 16;
                __builtin_amdgcn_global_load_lds(
                    (const __attribute__((address_space(1))) void*)(gxc + (base + lane) * 4),
                    (__attribute__((address_space(3))) void*)lp, 16, 0, 0);
            }
        }
    };

    // ---- prologue: DMA ch0; breg load (latency overlaps DMA); zero xs pad
    issue_x(gx);

    const int ctA = (6 * w) >> 2;          // wave w owns pairs p=6w..6w+5,
    const int ctB = (6 * w + 5) >> 2;      // p = ct*4 + rt (ctB = ctA+1)
    const int col0 = lane & 15;
    const int kq   = (lane >> 4) * 8;
    bf16x8 bregA[8], bregB[8];
    #pragma unroll
    for (int k0 = 0; k0 < 8; ++k0) {
        bf16x8 tA = *reinterpret_cast<const bf16x8*>(
            mt + (ctA * 16 + col0) * 256 + k0 * 32 + kq);
        bf16x8 tB = *reinterpret_cast<const bf16x8*>(
            mt + (ctB * 16 + col0) * 256 + k0 * 32 + kq);
        // launder: value opaque -> no remat from mt inside phase G (R9 mode)
        asm volatile("" : "+v"(tA), "+v"(tB));
        bregA[k0] = tA;
        bregB[k0] = tB;
    }

    // zero pad samples 7680..8319 once (convert never writes them)
    if (tid < 160) {
        unsigned a = phys(15360u + (unsigned)tid * 8u);
        *reinterpret_cast<uint2*>((char*)xs + a) = make_uint2(0u, 0u);
    }
    __syncthreads();   // drains DMA -> xf holds ch0

    for (int cc = 0; cc < CH_PB; ++cc) {
        const int par = cc & 1;

        // ---- convert: xf (LDS fp32) -> xs (bf16, phys-swizzled); zero psum
        if (tid < 96) psum[par][tid] = 0.f;
        #pragma unroll
        for (int i = 0; i < 8; ++i) {
            int c = i * 256 + tid;
            if (c < 1920) {
                f32x4 xv = *reinterpret_cast<const f32x4*>(&xf[4 * c]);
                unsigned b0 = f2bf(xv[0]), b1 = f2bf(xv[1]);
                unsigned b2 = f2bf(xv[2]), b3 = f2bf(xv[3]);
                uint2 pk; pk.x = b0 | (b1 << 16); pk.y = b2 | (b3 << 16);
                *reinterpret_cast<uint2*>((char*)xs + phys((unsigned)c * 8u)) = pk;
            }
        }
        __syncthreads();   // xs ready; xf free (convert reads done)

        // ---- prefetch next channel: DMA lands under phase G, drained by the
        // E-barrier ~2kcy later -> HBM latency hidden.
        if (cc + 1 < CH_PB) issue_x(gx + (size_t)(cc + 1) * T_LEN);

        // ---- phase G (R9/R10-verbatim): a[8] array, guards OUTSIDE k0 loop,
        // per-rt square-sum fold with junk-row mask.
        float pA = 0.f, pB = 0.f;
        const unsigned kq16 = (unsigned)((lane >> 4) * 16);
        #pragma unroll
        for (int rt = 0; rt < 4; ++rt) {
            const unsigned abase = (unsigned)(rt * 16 + (lane & 15)) * 256u;
            bf16x8 a[8];
            #pragma unroll
            for (int k0 = 0; k0 < 8; ++k0)
                a[k0] = *reinterpret_cast<const bf16x8*>(
                    (char*)xs + phys(abase + (unsigned)k0 * 64u + kq16));
            f32x4 accA = (f32x4){0.f, 0.f, 0.f, 0.f};
            f32x4 accB = (f32x4){0.f, 0.f, 0.f, 0.f};
            const bool oA = (unsigned)(ctA * 4 + rt - 6 * w) < 6u;
            const bool oB = (unsigned)(ctB * 4 + rt - 6 * w) < 6u;
            if (oA) {
                #pragma unroll
                for (int k0 = 0; k0 < 8; ++k0)
                    accA = __builtin_amdgcn_mfma_f32_16x16x32_bf16(
                        a[k0], bregA[k0], accA, 0, 0, 0);
            }
            if (oB) {
                #pragma unroll
                for (int k0 = 0; k0 < 8; ++k0)
                    accB = __builtin_amdgcn_mfma_f32_16x16x32_bf16(
                        a[k0], bregB[k0], accB, 0, 0, 0);
            }
            // C/D layout: col = lane&15, row = rt*16 + (lane>>4)*4 + r
            const int rowbase = rt * 16 + (lane >> 4) * 4;
            #pragma unroll
            for (int r = 0; r < 4; ++r) {
                if (rt < 3 || rowbase + r < NSEG) {   // mask junk rows 59..63
                    pA += accA[r] * accA[r];
                    pB += accB[r] * accB[r];
                }
            }
        }

        // ---- phase E: reduce row-groups, LDS atomics into psum[par]
        pA += __shfl_xor(pA, 16);  pA += __shfl_xor(pA, 32);
        pB += __shfl_xor(pB, 16);  pB += __shfl_xor(pB, 32);
        if (lane < 16) {
            atomicAdd(&psum[par][ctA * 16 + col0], pA);
            atomicAdd(&psum[par][ctB * 16 + col0], pB);
        }
        __syncthreads();   // psum ready; prefetch DMA drained (hidden under G)

        // ---- output (next iter's convert zeroes the OTHER psum slot)
        if (tid < NBINS) {
            const float CNORM = 2.0f / (24576.0f * 59.0f);  // fs*sum(w^2)=256*96
            float psd = (psum[par][2 * tid] + psum[par][2 * tid + 1]) * CNORM;
            out[(size_t)(ch0 + cc) * NBINS + tid] = log1pf(psd);
        }
    }
}

extern "C" void kernel_launch(void* const* d_in, const int* in_sizes, int n_in,
                              void* d_out, int out_size, void* d_ws, size_t ws_size,
                              hipStream_t stream) {
    const float* x = (const float*)d_in[0];
    float* out = (float*)d_out;
    unsigned short* mt = (unsigned short*)d_ws;   // 96*256*2 = 49152 B

    build_basis_kernel<<<96, 256, 0, stream>>>(mt);
    welch_main_kernel<<<NBLK, 256, 0, stream>>>(x, mt, out);
}

// Round 12
// 46.163 us; speedup vs baseline: 2.1718x; 2.1718x over previous
//
#include <hip/hip_runtime.h>
#include <hip/hip_bf16.h>
#include <math.h>

#define T_LEN   7680
#define NSEG    59
#define NBINS   45
#define CH_PB   8      // channels per block
#define NBLK    512    // 4096 / CH_PB ; = 2 blocks/CU exactly, no tail
#define NTHR    512    // 8 waves

using bf16x8 = __attribute__((ext_vector_type(8))) short;
using f32x4  = __attribute__((ext_vector_type(4))) float;

__device__ __forceinline__ unsigned f2bf(float f) {
    unsigned u = __builtin_bit_cast(unsigned, f);
    return (u + 0x7FFFu + ((u >> 16) & 1u)) >> 16;   // RNE fp32->bf16
}

// xs swizzle (R9-R11 proven): rows stride 256 B -> mix bits 8-10 into 4-6.
__device__ __forceinline__ unsigned phys(unsigned a) {
    return a ^ (((a >> 8) & 7u) << 4);
}
// mt_lds swizzle: rows stride 512 B -> mix bits 9-11 into 4-6. On the read
// side the within-row offset is < 512, so (a>>9)&7 == row&7 exactly.
__device__ __forceinline__ unsigned physB(unsigned a) {
    return a ^ (((a >> 9) & 7u) << 4);
}

// Basis table mt[96][256] bf16 (detrend+window folded; R2-proven math):
//   col j=2i: w_n*cos(2pi(i+1)n/256); col j=2i+1: -w_n*sin(...);
//   col 0 adds +0.25 (exact detrend correction for k=1 real part).
__global__ void build_basis_kernel(unsigned short* __restrict__ mt) {
    int j = blockIdx.x, n = threadIdx.x;
    const float TH = 0.02454369260617026f;           // 2*pi/256
    float w = 0.5f - 0.5f * cosf((float)n * TH);     // periodic hann
    float v = 0.f;
    if (j < 90) {
        int k = (j >> 1) + 1;
        int m = (k * n) & 255;                       // exact periodic reduction
        float th = (float)m * TH;
        v = (j & 1) ? (-w * sinf(th)) : (w * cosf(th));
        if (j == 0) v += 0.25f;                      // fold detrend into k=1 re
    }
    mt[j * 256 + n] = (unsigned short)f2bf(v);
}

// B-in-LDS redesign. Ledger of convicted patterns this avoids BY STRUCTURE:
//  - breg hoist (R7/R10/R11: allocator spills it; R8/R9: remat/stream puts
//    L2 latency on the MFMA path) -> B-frags are now ds_read_b128 from LDS.
//  - ownership guards around MFMA (R3-R5: absmax 4.2e-3) -> every wave has
//    exactly 3 unconditional pairs: (ct,rt) = ((w>>2)+2m, w&3), m=0..2.
//  - register prefetch across G (R7) -> none; cap-vs-demand (R6): cap 128
//    with natural demand ~70.
__global__ __launch_bounds__(NTHR, 4)
void welch_main_kernel(const float* __restrict__ x,
                       const unsigned short* __restrict__ mt,
                       float* __restrict__ out) {
    __shared__ __align__(16) unsigned short mt_lds[90 * 256];  // 46080 B
    __shared__ __align__(16) unsigned short xs[8320];          // 16640 B
    __shared__ float psum[2][96];                              //   768 B

    const int tid  = threadIdx.x;
    const int lane = tid & 63;
    const int w    = tid >> 6;            // 0..7
    const int ch0  = blockIdx.x * CH_PB;

    // ---- stage mt rows 0..89 into LDS once (2880 x 16B), physB-swizzled
    {
        const uint4* mt4 = reinterpret_cast<const uint4*>(mt);
        #pragma unroll
        for (int i = 0; i < 6; ++i) {
            int c = i * NTHR + tid;
            if (c < 2880) {
                uint4 v = mt4[c];
                *reinterpret_cast<uint4*>((char*)mt_lds + physB((unsigned)c * 16u)) = v;
            }
        }
    }
    // zero xs pad (samples 7680..8319) once; convert never writes them
    if (tid < 160) {
        unsigned a = phys(15360u + (unsigned)tid * 8u);
        *reinterpret_cast<uint2*>((char*)xs + a) = make_uint2(0u, 0u);
    }

    const int rt   = w & 3;               // row-tile, same for all 3 pairs
    const int ctb  = w >> 2;              // ct = ctb + 2m
    const int col0 = lane & 15;
    const unsigned kq16  = (unsigned)((lane >> 4) * 16);
    const unsigned abase = (unsigned)(rt * 16 + col0) * 256u;
    const int rowbase    = rt * 16 + (lane >> 4) * 4;

    for (int cc = 0; cc < CH_PB; ++cc) {
        const int par = cc & 1;
        const float* gx = x + (size_t)(ch0 + cc) * T_LEN;

        // ---- convert: global fp32 -> bf16 xs (phys-swizzled); zero psum[par]
        if (tid < 96) psum[par][tid] = 0.f;
        #pragma unroll
        for (int i = 0; i < 4; ++i) {
            int c = i * NTHR + tid;
            if (c < 1920) {
                f32x4 xv = *reinterpret_cast<const f32x4*>(gx + 4 * c);
                unsigned b0 = f2bf(xv[0]), b1 = f2bf(xv[1]);
                unsigned b2 = f2bf(xv[2]), b3 = f2bf(xv[3]);
                uint2 pk; pk.x = b0 | (b1 << 16); pk.y = b2 | (b3 << 16);
                *reinterpret_cast<uint2*>((char*)xs + phys((unsigned)c * 8u)) = pk;
            }
        }
        __syncthreads();   // xs + mt_lds (first iter) + psum ready

        // ---- A-fragments once per wave (shared by all 3 pairs)
        bf16x8 a[8];
        #pragma unroll
        for (int k0 = 0; k0 < 8; ++k0)
            a[k0] = *reinterpret_cast<const bf16x8*>(
                (char*)xs + phys(abase + (unsigned)k0 * 64u + kq16));

        // ---- 3 unconditional pairs: ct = ctb + 2m; B-frag from LDS per k0
        #pragma unroll
        for (int m = 0; m < 3; ++m) {
            const int ct = ctb + 2 * m;
            int j = ct * 16 + col0;
            if (j > 89) j = 89;            // dummy cols 90..95 -> col 89 data
            const unsigned bbase = (unsigned)j * 512u;
            const unsigned bswz  = (unsigned)((j & 7) << 4);
            f32x4 acc = (f32x4){0.f, 0.f, 0.f, 0.f};
            #pragma unroll
            for (int k0 = 0; k0 < 8; ++k0) {
                bf16x8 b = *reinterpret_cast<const bf16x8*>(
                    (char*)mt_lds + ((bbase + (unsigned)k0 * 64u + kq16) ^ bswz));
                acc = __builtin_amdgcn_mfma_f32_16x16x32_bf16(a[k0], b, acc, 0, 0, 0);
            }
            // square-sum; mask junk rows 59..63 (possible only at rt==3).
            // C/D layout: col = lane&15, row = rt*16 + (lane>>4)*4 + r.
            float p = 0.f;
            #pragma unroll
            for (int r = 0; r < 4; ++r)
                if (rt < 3 || rowbase + r < NSEG) p += acc[r] * acc[r];
            p += __shfl_xor(p, 16);
            p += __shfl_xor(p, 32);
            if (lane < 16) atomicAdd(&psum[par][ct * 16 + lane], p);
        }
        __syncthreads();   // psum[par] complete; xs free for next channel

        // ---- output (next iter zeroes the OTHER psum slot -> no extra barrier)
        if (tid < NBINS) {
            const float CNORM = 2.0f / (24576.0f * 59.0f);  // fs*sum(w^2)=256*96
            float psd = (psum[par][2 * tid] + psum[par][2 * tid + 1]) * CNORM;
            out[(size_t)(ch0 + cc) * NBINS + tid] = log1pf(psd);
        }
    }
}

extern "C" void kernel_launch(void* const* d_in, const int* in_sizes, int n_in,
                              void* d_out, int out_size, void* d_ws, size_t ws_size,
                              hipStream_t stream) {
    const float* x = (const float*)d_in[0];
    float* out = (float*)d_out;
    unsigned short* mt = (unsigned short*)d_ws;   // 96*256*2 = 49152 B

    build_basis_kernel<<<96, 256, 0, stream>>>(mt);
    welch_main_kernel<<<NBLK, NTHR, 0, stream>>>(x, mt, out);
}